// Round 22
// baseline (270.901 us; speedup 1.0000x reference)
//
#include <hip/hip_runtime.h>

#define NN  100000
#define FIN 165
#define HID 128
#define NBUCK 391        // ceil(NN/256), bucket = dst >> 8
#define CAP   9216       // fixed bucket capacity (mean 8192, sigma~90 -> 11 sigma)
#define KPAD 192         // FIN padded to 6 k-steps of 32
#define WS   196         // W LDS row stride in ushorts (98 dwords -> uniform 4-phase b64)
#define NBLK 256         // persistent bfill blocks (1 per CU)

typedef __attribute__((ext_vector_type(4))) float f32x4;
typedef __attribute__((ext_vector_type(8))) short short8;

// ws layout (4-byte units). h1 packed uint = bf16 pair (ch, ch+64) per node.
#define OFF_DINV   0
#define OFF_H1     100352
#define OFF_Z      (OFF_H1 + NN * 64)             // 6,500,352
#define OFF_ROWB   (OFF_Z + 2 * NN)               // 6,700,352
#define OFF_ROWE   (OFF_ROWB + 100352)
#define OFF_GCUR   (OFF_ROWE + 100352)
#define OFF_BUCK   (OFF_GCUR + 512)               // NBUCK*CAP
#define OFF_EDATA  (OFF_BUCK + NBUCK * CAP)       // NBUCK*CAP (bucket-local CSR)
#define OFF_WTHI   (OFF_EDATA + NBUCK * CAP)      // ~56.5 MB total

__device__ __forceinline__ unsigned bf16rne(float f) {
    unsigned u = __float_as_uint(f);
    return (u + 0x7FFFu + ((u >> 16) & 1u)) >> 16;
}

__device__ __forceinline__ float2 bf2_to_f2(unsigned int u) {
    float2 r;
    r.x = __uint_as_float(u << 16);
    r.y = __uint_as_float(u & 0xffff0000u);
    return r;
}

// fragment from LDS: k = base..base+3 and base+16..base+19
__device__ __forceinline__ short8 ldfrag(const ushort* p) {
    union { uint2 u[2]; short8 s; } f;
    f.u[0] = *(const uint2*)p;
    f.u[1] = *(const uint2*)(p + 16);
    return f.s;
}

// W1 -> bf16 (single RNE round), transposed to [ch][k], K zero-padded to KPAD.
// Also initializes gcur[b] = b*CAP (bump allocators for fixed-capacity buckets).
__global__ void k_wsplit(const float* __restrict__ W1, ushort* __restrict__ hi,
                         int* __restrict__ gcur) {
    int t = blockIdx.x * blockDim.x + threadIdx.x;
    if (t < 512) gcur[t] = t * CAP;
    if (t >= HID * KPAD) return;
    int ch = t / KPAD, k = t % KPAD;
    float v = (k < FIN) ? W1[k * HID + ch] : 0.0f;
    hi[ch * KPAD + k] = (ushort)bf16rne(v);
}

// single-pass bucket fill, persistent 256 blocks x 1024 threads (1 block/CU):
// per-(block,bucket) runs ~32 edges = 128B contiguous -> low write amp.
__global__ __launch_bounds__(1024) void k_bfill(const int* __restrict__ src,
        const int* __restrict__ dst, int* __restrict__ gcur,
        unsigned int* __restrict__ bucketed, int ne) {
    __shared__ int hist[NBUCK];
    __shared__ int lcur[NBUCK];
    for (int i = threadIdx.x; i < NBUCK; i += 1024) hist[i] = 0;
    __syncthreads();
    const int4* dst4 = (const int4*)dst;
    const int4* src4 = (const int4*)src;
    const int ne4 = ne >> 2;
    const int per4 = (ne4 + NBLK - 1) / NBLK;
    const int b0 = blockIdx.x * per4;
    const int b1 = min(ne4, b0 + per4);
    for (int e4 = b0 + (int)threadIdx.x; e4 < b1; e4 += 1024) {
        int4 v = dst4[e4];
        atomicAdd(&hist[v.x >> 8], 1);
        atomicAdd(&hist[v.y >> 8], 1);
        atomicAdd(&hist[v.z >> 8], 1);
        atomicAdd(&hist[v.w >> 8], 1);
    }
    if (blockIdx.x == 0 && threadIdx.x < (ne & 3))
        atomicAdd(&hist[dst[(ne & ~3) + threadIdx.x] >> 8], 1);
    __syncthreads();
    for (int i = threadIdx.x; i < NBUCK; i += 1024) {
        int h = hist[i];
        lcur[i] = h ? atomicAdd(&gcur[i], h) : 0;
    }
    __syncthreads();
#define PUT(D, S)                                                            \
    {                                                                        \
        int b_ = (D) >> 8;                                                   \
        int pos_ = atomicAdd(&lcur[b_], 1);                                  \
        if (pos_ < (b_ + 1) * CAP)                                           \
            bucketed[pos_] = (unsigned)(S) | ((unsigned)((D) & 255) << 24);  \
    }
    for (int e4 = b0 + (int)threadIdx.x; e4 < b1; e4 += 1024) {
        int4 d4 = dst4[e4];
        int4 s4 = src4[e4];
        PUT(d4.x, s4.x);
        PUT(d4.y, s4.y);
        PUT(d4.z, s4.z);
        PUT(d4.w, s4.w);
    }
    if (blockIdx.x == 0 && threadIdx.x < (ne & 3)) {
        int e = (ne & ~3) + threadIdx.x;
        PUT(dst[e], src[e]);
    }
#undef PUT
}

// FUSED: blocks [0, NBUCK) run the fine-sort body (bucket-local CSR: writes
// rowbeg/rowend + sorted edata at b*CAP — no global scan needed); blocks
// [NBUCK, NBUCK+ngemm) run the gemm1 body. fine is light and off gemm1's
// L2-miss path -> fused time ~ max(gemm1, fine).
__global__ __launch_bounds__(512) void k_fused2(
        const float* __restrict__ x, const ushort* __restrict__ wthi,
        unsigned* __restrict__ h1, int n,
        const int* __restrict__ gcur, const unsigned int* __restrict__ bucketed,
        int* __restrict__ edata, int* __restrict__ rowbeg,
        int* __restrict__ rowend, float* __restrict__ dinv) {
    __shared__ alignas(16) unsigned char smem[128 * WS * 2];   // 50.2 KB union

    if (blockIdx.x < NBUCK) {
        // ---------------- fine-sort body (512 threads) ----------------
        int* hist = (int*)smem;
        int* scan = hist + 256;
        int* lcur = scan + 256;
        const int b = blockIdx.x;
        const int tid = threadIdx.x;
        const int rbeg = b * CAP;
        const int cnt = min(gcur[b] - rbeg, CAP);
        if (tid < 256) hist[tid] = 0;
        __syncthreads();
        for (int j = tid; j < cnt; j += 512)
            atomicAdd(&hist[bucketed[rbeg + j] >> 24], 1);
        __syncthreads();
        if (tid < 256) scan[tid] = hist[tid];
        __syncthreads();
        for (int off = 1; off < 256; off <<= 1) {
            int t = 0;
            if (tid < 256 && tid >= off) t = scan[tid - off];
            __syncthreads();
            if (tid < 256) scan[tid] += t;
            __syncthreads();
        }
        if (tid < 256) {
            int c = hist[tid];
            int excl = scan[tid] - c;
            int d = b * 256 + tid;
            if (d < n) {
                rowbeg[d] = rbeg + excl;
                rowend[d] = rbeg + excl + c;
                dinv[d] = rsqrtf((float)c + 1.0f);   // +1 self-loop
            }
            lcur[tid] = rbeg + excl;
        }
        __syncthreads();
        for (int j = tid; j < cnt; j += 512) {
            unsigned p = bucketed[rbeg + j];
            int pos = atomicAdd(&lcur[p >> 24], 1);
            edata[pos] = (int)(p & 0x00FFFFFFu);
        }
        return;
    }

    // ---------------- gemm1 body (512 threads, 128 nodes) ----------------
    ushort* whi = (ushort*)smem;
    const int tid = threadIdx.x;
    const int node0 = (blockIdx.x - NBUCK) * 128;
    const int wv = tid >> 6, lane = tid & 63;      // wv = 0..7
    const int r15 = lane & 15, g = lane >> 4;

    // stage all of W: thread t covers ch = t>>2, quarter = t&3 (48 ushorts)
    {
        int ch = tid >> 2, q = tid & 3;
        int gb = ch * KPAD + q * 48;
        int lb = ch * WS + q * 48;
#pragma unroll
        for (int j = 0; j < 12; ++j) {
            uint2 v = *(const uint2*)&wthi[gb + j * 4];
            *(uint2*)&whi[lb + j * 4] = v;
        }
    }

    const int row = node0 + wv * 16 + r15;     // this lane's A-node
    const bool rowok = row < n;
    const float* xrow = x + (size_t)row * FIN;

    f32x4 acc[8];
#pragma unroll
    for (int ct = 0; ct < 8; ++ct) acc[ct] = (f32x4){0.f, 0.f, 0.f, 0.f};

    __syncthreads();                            // the ONLY barrier

    for (int ks = 0; ks < 6; ++ks) {
        unsigned hh[8];
#pragma unroll
        for (int j = 0; j < 4; ++j) {
            int k0 = ks * 32 + 4 * g + j;
            int k1 = k0 + 16;
            float v0 = (rowok && k0 < FIN) ? xrow[k0] : 0.0f;
            float v1 = (rowok && k1 < FIN) ? xrow[k1] : 0.0f;
            hh[j]     = bf16rne(v0);
            hh[4 + j] = bf16rne(v1);
        }
        union { unsigned u[4]; short8 s; } A;
        A.u[0] = hh[0] | (hh[1] << 16);
        A.u[1] = hh[2] | (hh[3] << 16);
        A.u[2] = hh[4] | (hh[5] << 16);
        A.u[3] = hh[6] | (hh[7] << 16);
#pragma unroll
        for (int ct = 0; ct < 8; ++ct) {
            short8 Bh = ldfrag(&whi[(ct * 16 + r15) * WS + ks * 32 + 4 * g]);
            acc[ct] = __builtin_amdgcn_mfma_f32_16x16x32_bf16(A.s, Bh, acc[ct], 0, 0, 0);
        }
    }

    // epilogue: C/D row = 4g + r, col = r15; pack (ct, ct+4) -> (ch, ch+64)
#pragma unroll
    for (int ct = 0; ct < 4; ++ct) {
#pragma unroll
        for (int r = 0; r < 4; ++r) {
            int node = node0 + wv * 16 + 4 * g + r;
            if (node < n) {
                unsigned p = bf16rne(acc[ct][r]) | (bf16rne(acc[ct + 4][r]) << 16);
                h1[node * 64 + ct * 16 + r15] = p;
            }
        }
    }
}

// one wave per dst node; 32 edges per iteration (8 per 16-lane group), with
// software-pipelined (src, norm) prefetch — 8 gathers in flight per lane.
// L2-fill-BW bound (~3.3 TB/s); deeper MLP targets any residual latency term.
__global__ __launch_bounds__(256) void k_agg_fused(const int* __restrict__ rowbeg,
        const int* __restrict__ rowend, const int* __restrict__ edata,
        const unsigned int* __restrict__ h1, const float* __restrict__ dinv,
        const float* __restrict__ b1, const float* __restrict__ W2,
        float* __restrict__ z, int n) {
    const int wid  = (blockIdx.x * blockDim.x + threadIdx.x) >> 6;
    const int lane = threadIdx.x & 63;
    if (wid >= n) return;
    const int d = wid;
    const int beg = rowbeg[d], end = rowend[d];
    const float di = dinv[d];
    const int grp = lane >> 4;          // edge-slot group
    const int sl  = lane & 15;          // channel slice: uints sl*4..sl*4+3

    float ax0, ax1, ax2, ax3, ay0, ay1, ay2, ay3;
    {   // self-loop (group 0 only, weight di^2)
        uint4 hv = *(const uint4*)&h1[d * 64 + sl * 4];
        float nm = (grp == 0) ? di * di : 0.0f;
        float2 f0 = bf2_to_f2(hv.x), f1 = bf2_to_f2(hv.y);
        float2 f2 = bf2_to_f2(hv.z), f3 = bf2_to_f2(hv.w);
        ax0 = f0.x * nm; ay0 = f0.y * nm;
        ax1 = f1.x * nm; ay1 = f1.y * nm;
        ax2 = f2.x * nm; ay2 = f2.y * nm;
        ax3 = f3.x * nm; ay3 = f3.y * nm;
    }

#define PRELOAD32(JB)                                                        \
    {                                                                        \
        _Pragma("unroll")                                                    \
        for (int q = 0; q < 8; ++q) {                                        \
            int i_ = (JB) + q * 4 + grp;                                     \
            int c_ = min(i_, end - 1);                                       \
            sA[q] = edata[c_];                                               \
            mA[q] = (i_ < end) ? dinv[sA[q]] * di : 0.0f;                    \
        }                                                                    \
    }
#define ACC(G, NM)                                                           \
    {                                                                        \
        float2 f;                                                            \
        f = bf2_to_f2((G).x); ax0 = fmaf(f.x, (NM), ax0); ay0 = fmaf(f.y, (NM), ay0); \
        f = bf2_to_f2((G).y); ax1 = fmaf(f.x, (NM), ax1); ay1 = fmaf(f.y, (NM), ay1); \
        f = bf2_to_f2((G).z); ax2 = fmaf(f.x, (NM), ax2); ay2 = fmaf(f.y, (NM), ay2); \
        f = bf2_to_f2((G).w); ax3 = fmaf(f.x, (NM), ax3); ay3 = fmaf(f.y, (NM), ay3); \
    }

    if (beg < end) {
        int sA[8];
        float mA[8];
        PRELOAD32(beg);
        for (int j = beg; j < end; j += 32) {
            uint4 gv[8];
#pragma unroll
            for (int q = 0; q < 8; ++q)
                gv[q] = *(const uint4*)&h1[sA[q] * 64 + sl * 4];
            float wv_[8];
#pragma unroll
            for (int q = 0; q < 8; ++q) wv_[q] = mA[q];
            int jn = j + 32;
            if (jn < end) PRELOAD32(jn);        // wave-uniform branch
#pragma unroll
            for (int q = 0; q < 8; ++q) ACC(gv[q], wv_[q]);
        }
    }
#undef PRELOAD32
#undef ACC

    ax0 += __shfl_xor(ax0, 16, 64); ax0 += __shfl_xor(ax0, 32, 64);
    ax1 += __shfl_xor(ax1, 16, 64); ax1 += __shfl_xor(ax1, 32, 64);
    ax2 += __shfl_xor(ax2, 16, 64); ax2 += __shfl_xor(ax2, 32, 64);
    ax3 += __shfl_xor(ax3, 16, 64); ax3 += __shfl_xor(ax3, 32, 64);
    ay0 += __shfl_xor(ay0, 16, 64); ay0 += __shfl_xor(ay0, 32, 64);
    ay1 += __shfl_xor(ay1, 16, 64); ay1 += __shfl_xor(ay1, 32, 64);
    ay2 += __shfl_xor(ay2, 16, 64); ay2 += __shfl_xor(ay2, 32, 64);
    ay3 += __shfl_xor(ay3, 16, 64); ay3 += __shfl_xor(ay3, 32, 64);
    // epilogue: channels c=sl*4+q (ax) and c+64 (ay); relu + W2 dot
    const int c = sl * 4;
    float4 bA = *(const float4*)&b1[c];
    float4 bB = *(const float4*)&b1[c + 64];
    float v00 = ax0 + bA.x; v00 = v00 > 0.f ? v00 : 0.f;
    float v01 = ax1 + bA.y; v01 = v01 > 0.f ? v01 : 0.f;
    float v02 = ax2 + bA.z; v02 = v02 > 0.f ? v02 : 0.f;
    float v03 = ax3 + bA.w; v03 = v03 > 0.f ? v03 : 0.f;
    float v10 = ay0 + bB.x; v10 = v10 > 0.f ? v10 : 0.f;
    float v11 = ay1 + bB.y; v11 = v11 > 0.f ? v11 : 0.f;
    float v12 = ay2 + bB.z; v12 = v12 > 0.f ? v12 : 0.f;
    float v13 = ay3 + bB.w; v13 = v13 > 0.f ? v13 : 0.f;
    float4 wA0 = *(const float4*)&W2[c * 2];
    float4 wA1 = *(const float4*)&W2[c * 2 + 4];
    float4 wB0 = *(const float4*)&W2[(c + 64) * 2];
    float4 wB1 = *(const float4*)&W2[(c + 64) * 2 + 4];
    float p0 = v00 * wA0.x + v01 * wA0.z + v02 * wA1.x + v03 * wA1.z
             + v10 * wB0.x + v11 * wB0.z + v12 * wB1.x + v13 * wB1.z;
    float p1 = v00 * wA0.y + v01 * wA0.w + v02 * wA1.y + v03 * wA1.w
             + v10 * wB0.y + v11 * wB0.w + v12 * wB1.y + v13 * wB1.w;
#pragma unroll
    for (int m = 8; m >= 1; m >>= 1) {
        p0 += __shfl_xor(p0, m, 64);
        p1 += __shfl_xor(p1, m, 64);
    }
    if (lane == 0) *(float2*)&z[d * 2] = make_float2(p0, p1);
}

// layer-2: 16-lane group per dst node, gather-side over the bucket-local CSR
__global__ __launch_bounds__(256) void k_out(const int* __restrict__ rowbeg,
        const int* __restrict__ rowend, const int* __restrict__ edata,
        const float* __restrict__ z, const float* __restrict__ dinv,
        const float* __restrict__ b2, float* __restrict__ out, int n) {
    int g = (blockIdx.x * blockDim.x + threadIdx.x) >> 4;
    int l = threadIdx.x & 15;
    if (g >= n) return;
    int beg = rowbeg[g], end = rowend[g];
    float di = dinv[g];
    float o0 = 0.0f, o1 = 0.0f;
    for (int j = beg + l; j < end; j += 16) {
        int s = edata[j];
        float nm = dinv[s] * di;
        float2 zs = *(const float2*)&z[s * 2];
        o0 = fmaf(zs.x, nm, o0);
        o1 = fmaf(zs.y, nm, o1);
    }
#pragma unroll
    for (int m = 8; m >= 1; m >>= 1) {
        o0 += __shfl_xor(o0, m, 16);
        o1 += __shfl_xor(o1, m, 16);
    }
    if (l == 0) {
        float2 zd = *(const float2*)&z[g * 2];
        float s2 = di * di;
        out[g * 2]     = fmaf(zd.x, s2, b2[0]) + o0;
        out[g * 2 + 1] = fmaf(zd.y, s2, b2[1]) + o1;
    }
}

extern "C" void kernel_launch(void* const* d_in, const int* in_sizes, int n_in,
                              void* d_out, int out_size, void* d_ws, size_t ws_size,
                              hipStream_t stream) {
    const float* x  = (const float*)d_in[0];
    const int*   ei = (const int*)d_in[1];
    const float* W1 = (const float*)d_in[2];
    const float* b1 = (const float*)d_in[3];
    const float* W2 = (const float*)d_in[4];
    const float* b2 = (const float*)d_in[5];
    float* out = (float*)d_out;

    const int n  = in_sizes[0] / FIN;   // 100000
    const int ne = in_sizes[1] / 2;     // 3200000
    const int* src = ei;
    const int* dst = ei + ne;

    float* ws     = (float*)d_ws;
    float* dinv   = ws + OFF_DINV;
    unsigned int* h1 = (unsigned int*)(ws + OFF_H1);
    float* z      = ws + OFF_Z;
    int*   rowbeg = (int*)(ws + OFF_ROWB);
    int*   rowend = (int*)(ws + OFF_ROWE);
    int*   gcur   = (int*)(ws + OFF_GCUR);
    unsigned int* bucketed = (unsigned int*)(ws + OFF_BUCK);
    int*   edata  = (int*)(ws + OFF_EDATA);
    ushort* wthi  = (ushort*)(ws + OFF_WTHI);

    const int ngemm = (n + 127) / 128;           // 782

    k_wsplit<<<(HID * KPAD + 255) / 256, 256, 0, stream>>>(W1, wthi, gcur);
    k_bfill<<<NBLK, 1024, 0, stream>>>(src, dst, gcur, bucketed, ne);
    k_fused2<<<NBUCK + ngemm, 512, 0, stream>>>(x, wthi, h1, n,
                                                gcur, bucketed, edata,
                                                rowbeg, rowend, dinv);
    k_agg_fused<<<((size_t)n * 64 + 255) / 256, 256, 0, stream>>>(
        rowbeg, rowend, edata, h1, dinv, b1, W2, z, n);
    k_out<<<(n * 16 + 255) / 256, 256, 0, stream>>>(rowbeg, rowend, edata,
                                                    z, dinv, b2, out, n);
}

// Round 24
// 221.704 us; speedup vs baseline: 1.2219x; 1.2219x over previous
//
#include <hip/hip_runtime.h>

#define NN  100000
#define FIN 165
#define HID 128
#define NBUCK 391        // ceil(NN/256), bucket = dst >> 8
#define CAP   9216       // fixed bucket capacity (mean 8192, sigma~90 -> 11 sigma)
#define KPAD 192         // FIN padded to 6 k-steps of 32
#define WS   196         // W LDS row stride in ushorts (98 dwords -> uniform 4-phase b64)
#define NBLK 256         // persistent bfill blocks (1 per CU)

typedef __attribute__((ext_vector_type(4))) float f32x4;
typedef __attribute__((ext_vector_type(8))) short short8;

// ws layout (4-byte units). h1 packed uint = bf16 pair (ch, ch+64) per node.
#define OFF_DINV   0
#define OFF_H1     100352
#define OFF_Z      (OFF_H1 + NN * 64)             // 6,500,352
#define OFF_ROWB   (OFF_Z + 2 * NN)               // 6,700,352
#define OFF_ROWE   (OFF_ROWB + 100352)
#define OFF_GCUR   (OFF_ROWE + 100352)
#define OFF_BUCK   (OFF_GCUR + 512)               // NBUCK*CAP
#define OFF_EDATA  (OFF_BUCK + NBUCK * CAP)       // NBUCK*CAP (bucket-local CSR)
#define OFF_WTHI   (OFF_EDATA + NBUCK * CAP)      // ~56.5 MB total

__device__ __forceinline__ unsigned bf16rne(float f) {
    unsigned u = __float_as_uint(f);
    return (u + 0x7FFFu + ((u >> 16) & 1u)) >> 16;
}

__device__ __forceinline__ float2 bf2_to_f2(unsigned int u) {
    float2 r;
    r.x = __uint_as_float(u << 16);
    r.y = __uint_as_float(u & 0xffff0000u);
    return r;
}

// fragment from LDS: k = base..base+3 and base+16..base+19
__device__ __forceinline__ short8 ldfrag(const ushort* p) {
    union { uint2 u[2]; short8 s; } f;
    f.u[0] = *(const uint2*)p;
    f.u[1] = *(const uint2*)(p + 16);
    return f.s;
}

// W1 -> bf16 (single RNE round), transposed to [ch][k], K zero-padded to KPAD.
// Also initializes gcur[b] = b*CAP (bump allocators for fixed-capacity buckets).
__global__ void k_wsplit(const float* __restrict__ W1, ushort* __restrict__ hi,
                         int* __restrict__ gcur) {
    int t = blockIdx.x * blockDim.x + threadIdx.x;
    if (t < 512) gcur[t] = t * CAP;
    if (t >= HID * KPAD) return;
    int ch = t / KPAD, k = t % KPAD;
    float v = (k < FIN) ? W1[k * HID + ch] : 0.0f;
    hi[ch * KPAD + k] = (ushort)bf16rne(v);
}

// single-pass bucket fill, persistent 256 blocks x 1024 threads (1 block/CU):
// per-(block,bucket) runs ~32 edges = 128B contiguous -> low write amp.
__global__ __launch_bounds__(1024) void k_bfill(const int* __restrict__ src,
        const int* __restrict__ dst, int* __restrict__ gcur,
        unsigned int* __restrict__ bucketed, int ne) {
    __shared__ int hist[NBUCK];
    __shared__ int lcur[NBUCK];
    for (int i = threadIdx.x; i < NBUCK; i += 1024) hist[i] = 0;
    __syncthreads();
    const int4* dst4 = (const int4*)dst;
    const int4* src4 = (const int4*)src;
    const int ne4 = ne >> 2;
    const int per4 = (ne4 + NBLK - 1) / NBLK;
    const int b0 = blockIdx.x * per4;
    const int b1 = min(ne4, b0 + per4);
    for (int e4 = b0 + (int)threadIdx.x; e4 < b1; e4 += 1024) {
        int4 v = dst4[e4];
        atomicAdd(&hist[v.x >> 8], 1);
        atomicAdd(&hist[v.y >> 8], 1);
        atomicAdd(&hist[v.z >> 8], 1);
        atomicAdd(&hist[v.w >> 8], 1);
    }
    if (blockIdx.x == 0 && threadIdx.x < (ne & 3))
        atomicAdd(&hist[dst[(ne & ~3) + threadIdx.x] >> 8], 1);
    __syncthreads();
    for (int i = threadIdx.x; i < NBUCK; i += 1024) {
        int h = hist[i];
        lcur[i] = h ? atomicAdd(&gcur[i], h) : 0;
    }
    __syncthreads();
#define PUT(D, S)                                                            \
    {                                                                        \
        int b_ = (D) >> 8;                                                   \
        int pos_ = atomicAdd(&lcur[b_], 1);                                  \
        if (pos_ < (b_ + 1) * CAP)                                           \
            bucketed[pos_] = (unsigned)(S) | ((unsigned)((D) & 255) << 24);  \
    }
    for (int e4 = b0 + (int)threadIdx.x; e4 < b1; e4 += 1024) {
        int4 d4 = dst4[e4];
        int4 s4 = src4[e4];
        PUT(d4.x, s4.x);
        PUT(d4.y, s4.y);
        PUT(d4.z, s4.z);
        PUT(d4.w, s4.w);
    }
    if (blockIdx.x == 0 && threadIdx.x < (ne & 3)) {
        int e = (ne & ~3) + threadIdx.x;
        PUT(dst[e], src[e]);
    }
#undef PUT
}

// FUSED: blocks [0, NBUCK) run the fine-sort body (bucket-local CSR: writes
// rowbeg/rowend + sorted edata at b*CAP — no global scan needed); blocks
// [NBUCK, NBUCK+ngemm) run the gemm1 body. fine is light and off gemm1's
// L2-miss path -> fused time ~ max(gemm1, fine).
__global__ __launch_bounds__(512) void k_fused2(
        const float* __restrict__ x, const ushort* __restrict__ wthi,
        unsigned* __restrict__ h1, int n,
        const int* __restrict__ gcur, const unsigned int* __restrict__ bucketed,
        int* __restrict__ edata, int* __restrict__ rowbeg,
        int* __restrict__ rowend, float* __restrict__ dinv) {
    __shared__ alignas(16) unsigned char smem[128 * WS * 2];   // 50.2 KB union

    if (blockIdx.x < NBUCK) {
        // ---------------- fine-sort body (512 threads) ----------------
        int* hist = (int*)smem;
        int* scan = hist + 256;
        int* lcur = scan + 256;
        const int b = blockIdx.x;
        const int tid = threadIdx.x;
        const int rbeg = b * CAP;
        const int cnt = min(gcur[b] - rbeg, CAP);
        if (tid < 256) hist[tid] = 0;
        __syncthreads();
        for (int j = tid; j < cnt; j += 512)
            atomicAdd(&hist[bucketed[rbeg + j] >> 24], 1);
        __syncthreads();
        if (tid < 256) scan[tid] = hist[tid];
        __syncthreads();
        for (int off = 1; off < 256; off <<= 1) {
            int t = 0;
            if (tid < 256 && tid >= off) t = scan[tid - off];
            __syncthreads();
            if (tid < 256) scan[tid] += t;
            __syncthreads();
        }
        if (tid < 256) {
            int c = hist[tid];
            int excl = scan[tid] - c;
            int d = b * 256 + tid;
            if (d < n) {
                rowbeg[d] = rbeg + excl;
                rowend[d] = rbeg + excl + c;
                dinv[d] = rsqrtf((float)c + 1.0f);   // +1 self-loop
            }
            lcur[tid] = rbeg + excl;
        }
        __syncthreads();
        for (int j = tid; j < cnt; j += 512) {
            unsigned p = bucketed[rbeg + j];
            int pos = atomicAdd(&lcur[p >> 24], 1);
            edata[pos] = (int)(p & 0x00FFFFFFu);
        }
        return;
    }

    // ---------------- gemm1 body (512 threads, 128 nodes) ----------------
    ushort* whi = (ushort*)smem;
    const int tid = threadIdx.x;
    const int node0 = (blockIdx.x - NBUCK) * 128;
    const int wv = tid >> 6, lane = tid & 63;      // wv = 0..7
    const int r15 = lane & 15, g = lane >> 4;

    // stage all of W: thread t covers ch = t>>2, quarter = t&3 (48 ushorts)
    {
        int ch = tid >> 2, q = tid & 3;
        int gb = ch * KPAD + q * 48;
        int lb = ch * WS + q * 48;
#pragma unroll
        for (int j = 0; j < 12; ++j) {
            uint2 v = *(const uint2*)&wthi[gb + j * 4];
            *(uint2*)&whi[lb + j * 4] = v;
        }
    }

    const int row = node0 + wv * 16 + r15;     // this lane's A-node
    const bool rowok = row < n;
    const float* xrow = x + (size_t)row * FIN;

    f32x4 acc[8];
#pragma unroll
    for (int ct = 0; ct < 8; ++ct) acc[ct] = (f32x4){0.f, 0.f, 0.f, 0.f};

    __syncthreads();                            // the ONLY barrier

    for (int ks = 0; ks < 6; ++ks) {
        unsigned hh[8];
#pragma unroll
        for (int j = 0; j < 4; ++j) {
            int k0 = ks * 32 + 4 * g + j;
            int k1 = k0 + 16;
            float v0 = (rowok && k0 < FIN) ? xrow[k0] : 0.0f;
            float v1 = (rowok && k1 < FIN) ? xrow[k1] : 0.0f;
            hh[j]     = bf16rne(v0);
            hh[4 + j] = bf16rne(v1);
        }
        union { unsigned u[4]; short8 s; } A;
        A.u[0] = hh[0] | (hh[1] << 16);
        A.u[1] = hh[2] | (hh[3] << 16);
        A.u[2] = hh[4] | (hh[5] << 16);
        A.u[3] = hh[6] | (hh[7] << 16);
#pragma unroll
        for (int ct = 0; ct < 8; ++ct) {
            short8 Bh = ldfrag(&whi[(ct * 16 + r15) * WS + ks * 32 + 4 * g]);
            acc[ct] = __builtin_amdgcn_mfma_f32_16x16x32_bf16(A.s, Bh, acc[ct], 0, 0, 0);
        }
    }

    // epilogue: C/D row = 4g + r, col = r15; pack (ct, ct+4) -> (ch, ch+64)
#pragma unroll
    for (int ct = 0; ct < 4; ++ct) {
#pragma unroll
        for (int r = 0; r < 4; ++r) {
            int node = node0 + wv * 16 + 4 * g + r;
            if (node < n) {
                unsigned p = bf16rne(acc[ct][r]) | (bf16rne(acc[ct + 4][r]) << 16);
                h1[node * 64 + ct * 16 + r15] = p;
            }
        }
    }
}

// one wave per dst node; 16 edges per iteration (4 per 16-lane group), with
// software-pipelined (src, norm) prefetch (R21-proven form: VGPR 32, ~78%
// occupancy — agg's 3.3 TB/s L2-fill BW is sustained by wave count, not MLP
// depth; the R22 8-deep variant halved occupancy and lost 30% BW).
__global__ __launch_bounds__(256) void k_agg_fused(const int* __restrict__ rowbeg,
        const int* __restrict__ rowend, const int* __restrict__ edata,
        const unsigned int* __restrict__ h1, const float* __restrict__ dinv,
        const float* __restrict__ b1, const float* __restrict__ W2,
        float* __restrict__ z, int n) {
    const int wid  = (blockIdx.x * blockDim.x + threadIdx.x) >> 6;
    const int lane = threadIdx.x & 63;
    if (wid >= n) return;
    const int d = wid;
    const int beg = rowbeg[d], end = rowend[d];
    const float di = dinv[d];
    const int grp = lane >> 4;          // which edge slot of the 4-pack
    const int sl  = lane & 15;          // channel slice: uints sl*4..sl*4+3

    float ax0, ax1, ax2, ax3, ay0, ay1, ay2, ay3;
    {   // self-loop (group 0 only, weight di^2)
        uint4 hv = *(const uint4*)&h1[d * 64 + sl * 4];
        float nm = (grp == 0) ? di * di : 0.0f;
        float2 f0 = bf2_to_f2(hv.x), f1 = bf2_to_f2(hv.y);
        float2 f2 = bf2_to_f2(hv.z), f3 = bf2_to_f2(hv.w);
        ax0 = f0.x * nm; ay0 = f0.y * nm;
        ax1 = f1.x * nm; ay1 = f1.y * nm;
        ax2 = f2.x * nm; ay2 = f2.y * nm;
        ax3 = f3.x * nm; ay3 = f3.y * nm;
    }

#define PRELOAD(JB)                                                          \
    {                                                                        \
        int i0 = (JB) + grp, i1 = (JB) + 4 + grp,                            \
            i2 = (JB) + 8 + grp, i3 = (JB) + 12 + grp;                       \
        int c0 = min(i0, end - 1), c1 = min(i1, end - 1);                    \
        int c2 = min(i2, end - 1), c3 = min(i3, end - 1);                    \
        s0 = edata[c0]; s1 = edata[c1]; s2 = edata[c2]; s3 = edata[c3];      \
        m0 = (i0 < end) ? dinv[s0] * di : 0.0f;                              \
        m1 = (i1 < end) ? dinv[s1] * di : 0.0f;                              \
        m2 = (i2 < end) ? dinv[s2] * di : 0.0f;                              \
        m3 = (i3 < end) ? dinv[s3] * di : 0.0f;                              \
    }
#define ACC(G, NM)                                                           \
    {                                                                        \
        float2 f;                                                            \
        f = bf2_to_f2((G).x); ax0 = fmaf(f.x, (NM), ax0); ay0 = fmaf(f.y, (NM), ay0); \
        f = bf2_to_f2((G).y); ax1 = fmaf(f.x, (NM), ax1); ay1 = fmaf(f.y, (NM), ay1); \
        f = bf2_to_f2((G).z); ax2 = fmaf(f.x, (NM), ax2); ay2 = fmaf(f.y, (NM), ay2); \
        f = bf2_to_f2((G).w); ax3 = fmaf(f.x, (NM), ax3); ay3 = fmaf(f.y, (NM), ay3); \
    }

    if (beg < end) {
        int s0, s1, s2, s3;
        float m0, m1, m2, m3;
        PRELOAD(beg);
        for (int j = beg; j < end; j += 16) {
            uint4 g0 = *(const uint4*)&h1[s0 * 64 + sl * 4];
            uint4 g1 = *(const uint4*)&h1[s1 * 64 + sl * 4];
            uint4 g2 = *(const uint4*)&h1[s2 * 64 + sl * 4];
            uint4 g3 = *(const uint4*)&h1[s3 * 64 + sl * 4];
            float w0 = m0, w1 = m1, w2 = m2, w3 = m3;
            int jn = j + 16;
            if (jn < end) PRELOAD(jn);          // wave-uniform branch
            ACC(g0, w0); ACC(g1, w1); ACC(g2, w2); ACC(g3, w3);
        }
    }
#undef PRELOAD
#undef ACC

    ax0 += __shfl_xor(ax0, 16, 64); ax0 += __shfl_xor(ax0, 32, 64);
    ax1 += __shfl_xor(ax1, 16, 64); ax1 += __shfl_xor(ax1, 32, 64);
    ax2 += __shfl_xor(ax2, 16, 64); ax2 += __shfl_xor(ax2, 32, 64);
    ax3 += __shfl_xor(ax3, 16, 64); ax3 += __shfl_xor(ax3, 32, 64);
    ay0 += __shfl_xor(ay0, 16, 64); ay0 += __shfl_xor(ay0, 32, 64);
    ay1 += __shfl_xor(ay1, 16, 64); ay1 += __shfl_xor(ay1, 32, 64);
    ay2 += __shfl_xor(ay2, 16, 64); ay2 += __shfl_xor(ay2, 32, 64);
    ay3 += __shfl_xor(ay3, 16, 64); ay3 += __shfl_xor(ay3, 32, 64);
    // epilogue: channels c=sl*4+q (ax) and c+64 (ay); relu + W2 dot
    const int c = sl * 4;
    float4 bA = *(const float4*)&b1[c];
    float4 bB = *(const float4*)&b1[c + 64];
    float v00 = ax0 + bA.x; v00 = v00 > 0.f ? v00 : 0.f;
    float v01 = ax1 + bA.y; v01 = v01 > 0.f ? v01 : 0.f;
    float v02 = ax2 + bA.z; v02 = v02 > 0.f ? v02 : 0.f;
    float v03 = ax3 + bA.w; v03 = v03 > 0.f ? v03 : 0.f;
    float v10 = ay0 + bB.x; v10 = v10 > 0.f ? v10 : 0.f;
    float v11 = ay1 + bB.y; v11 = v11 > 0.f ? v11 : 0.f;
    float v12 = ay2 + bB.z; v12 = v12 > 0.f ? v12 : 0.f;
    float v13 = ay3 + bB.w; v13 = v13 > 0.f ? v13 : 0.f;
    float4 wA0 = *(const float4*)&W2[c * 2];            // rows c, c+1
    float4 wA1 = *(const float4*)&W2[c * 2 + 4];        // rows c+2, c+3
    float4 wB0 = *(const float4*)&W2[(c + 64) * 2];     // rows c+64, c+65
    float4 wB1 = *(const float4*)&W2[(c + 64) * 2 + 4]; // rows c+66, c+67
    float p0 = v00 * wA0.x + v01 * wA0.z + v02 * wA1.x + v03 * wA1.z
             + v10 * wB0.x + v11 * wB0.z + v12 * wB1.x + v13 * wB1.z;
    float p1 = v00 * wA0.y + v01 * wA0.w + v02 * wA1.y + v03 * wA1.w
             + v10 * wB0.y + v11 * wB0.w + v12 * wB1.y + v13 * wB1.w;
#pragma unroll
    for (int m = 8; m >= 1; m >>= 1) {
        p0 += __shfl_xor(p0, m, 64);
        p1 += __shfl_xor(p1, m, 64);
    }
    if (lane == 0) *(float2*)&z[d * 2] = make_float2(p0, p1);
}

// layer-2: 16-lane group per dst node, gather-side over the bucket-local CSR
__global__ __launch_bounds__(256) void k_out(const int* __restrict__ rowbeg,
        const int* __restrict__ rowend, const int* __restrict__ edata,
        const float* __restrict__ z, const float* __restrict__ dinv,
        const float* __restrict__ b2, float* __restrict__ out, int n) {
    int g = (blockIdx.x * blockDim.x + threadIdx.x) >> 4;
    int l = threadIdx.x & 15;
    if (g >= n) return;
    int beg = rowbeg[g], end = rowend[g];
    float di = dinv[g];
    float o0 = 0.0f, o1 = 0.0f;
    for (int j = beg + l; j < end; j += 16) {
        int s = edata[j];
        float nm = dinv[s] * di;
        float2 zs = *(const float2*)&z[s * 2];
        o0 = fmaf(zs.x, nm, o0);
        o1 = fmaf(zs.y, nm, o1);
    }
#pragma unroll
    for (int m = 8; m >= 1; m >>= 1) {
        o0 += __shfl_xor(o0, m, 16);
        o1 += __shfl_xor(o1, m, 16);
    }
    if (l == 0) {
        float2 zd = *(const float2*)&z[g * 2];
        float s2 = di * di;
        out[g * 2]     = fmaf(zd.x, s2, b2[0]) + o0;
        out[g * 2 + 1] = fmaf(zd.y, s2, b2[1]) + o1;
    }
}

extern "C" void kernel_launch(void* const* d_in, const int* in_sizes, int n_in,
                              void* d_out, int out_size, void* d_ws, size_t ws_size,
                              hipStream_t stream) {
    const float* x  = (const float*)d_in[0];
    const int*   ei = (const int*)d_in[1];
    const float* W1 = (const float*)d_in[2];
    const float* b1 = (const float*)d_in[3];
    const float* W2 = (const float*)d_in[4];
    const float* b2 = (const float*)d_in[5];
    float* out = (float*)d_out;

    const int n  = in_sizes[0] / FIN;   // 100000
    const int ne = in_sizes[1] / 2;     // 3200000
    const int* src = ei;
    const int* dst = ei + ne;

    float* ws     = (float*)d_ws;
    float* dinv   = ws + OFF_DINV;
    unsigned int* h1 = (unsigned int*)(ws + OFF_H1);
    float* z      = ws + OFF_Z;
    int*   rowbeg = (int*)(ws + OFF_ROWB);
    int*   rowend = (int*)(ws + OFF_ROWE);
    int*   gcur   = (int*)(ws + OFF_GCUR);
    unsigned int* bucketed = (unsigned int*)(ws + OFF_BUCK);
    int*   edata  = (int*)(ws + OFF_EDATA);
    ushort* wthi  = (ushort*)(ws + OFF_WTHI);

    const int ngemm = (n + 127) / 128;           // 782

    k_wsplit<<<(HID * KPAD + 255) / 256, 256, 0, stream>>>(W1, wthi, gcur);
    k_bfill<<<NBLK, 1024, 0, stream>>>(src, dst, gcur, bucketed, ne);
    k_fused2<<<NBUCK + ngemm, 512, 0, stream>>>(x, wthi, h1, n,
                                                gcur, bucketed, edata,
                                                rowbeg, rowend, dinv);
    k_agg_fused<<<((size_t)n * 64 + 255) / 256, 256, 0, stream>>>(
        rowbeg, rowend, edata, h1, dinv, b1, W2, z, n);
    k_out<<<(n * 16 + 255) / 256, 256, 0, stream>>>(rowbeg, rowend, edata,
                                                    z, dinv, b2, out, n);
}